// Round 7
// baseline (158.236 us; speedup 1.0000x reference)
//
#include <hip/hip_runtime.h>
#include <math.h>

// fab_penalty_ls_curve — R10: eps_x rolling chain + fused last-block finish.
// R9b post-mortem: partial ~38us (below the harness's 41us/256MB workspace
// fills, which now top the dispatch list and are untouchable). Packing gained
// only ~4us: cross-pair movs + scalar transcendentals + addressing carry ~2x
// the naive op count. Fixed overhead ~74us dominates dur_us.
// R10 cuts:
// (1) eps_x chain: exn/ex/exs at point i are eps_x(i-1..i+1) — keep a 3-deep
//     rolling chain, compute only eps_x(i+2) fresh (1 sub+fma instead of 3).
//     The raw diff Fc-Dc doubles as the future exy center diff (gc chain);
//     exy re-expressed as (G[j+1]-G[j-1])*s — verified bit-identical per
//     component to R9's (Dr1-Br1)-(Dl1-Bl1) form. Drops rows A and Bc.
// (2) fused finish: per-block plain f64 store -> __threadfence -> u32
//     atomicAdd on a self-resetting __device__ counter (NOT workspace: it is
//     poison-filled); last block replays the finish reduction bit-identically
//     and writes out. ONE u32 atomic per block at block END — unlike R2/R3's
//     regression (per-block f64 atomic + mid-kernel ACQ_REL). No spin-wait.
// Spill tripwire: WRITE_SIZE must stay tiny. Assumes Wn % (2*BLOCK_X) == 0.

#define BLOCK_X 256
#define ROWS_PER 16

typedef float f32x2 __attribute__((ext_vector_type(2)));

__device__ __forceinline__ f32x2 mk2(float a, float b) { f32x2 v; v.x = a; v.y = b; return v; }
__device__ __forceinline__ f32x2 sp2(float a) { return mk2(a, a); }

#if __has_builtin(__builtin_elementwise_fma)
__device__ __forceinline__ f32x2 fma2(f32x2 a, f32x2 b, f32x2 c) { return __builtin_elementwise_fma(a, b, c); }
#else
__device__ __forceinline__ f32x2 fma2(f32x2 a, f32x2 b, f32x2 c) { return mk2(fmaf(a.x, b.x, c.x), fmaf(a.y, b.y, c.y)); }
#endif
#if __has_builtin(__builtin_elementwise_max)
__device__ __forceinline__ f32x2 max2(f32x2 a, f32x2 b) { return __builtin_elementwise_max(a, b); }
#else
__device__ __forceinline__ f32x2 max2(f32x2 a, f32x2 b) { return mk2(fmaxf(a.x, b.x), fmaxf(a.y, b.y)); }
#endif
__device__ __forceinline__ f32x2 abs2(f32x2 a) { return mk2(fabsf(a.x), fabsf(a.y)); }

__device__ unsigned int g_count = 0;   // last-block election; self-resets

// ---- scalar helpers (YB path + per-component transcendentals) ----

// atan(v / c) with v > 0, given rv ~= 1/v. Max abs err ~1e-5 rad.
__device__ __forceinline__ float fast_atan_ratio(float v, float c, float rv)
{
    const float rc = __builtin_amdgcn_rcpf(c);
    const float q  = v * rc;
    const float iq = c * rv;
    const bool  big = fabsf(q) > 1.0f;
    const float t  = big ? iq : q;
    const float s  = t * t;
    float p = fmaf(s, -0.01172120f, 0.05265332f);
    p = fmaf(s, p, -0.11643287f);
    p = fmaf(s, p,  0.19354346f);
    p = fmaf(s, p, -0.33262347f);
    p = fmaf(s, p,  0.99997726f);
    const float at = p * t;
    const float hp = copysignf(1.57079632679f, q);
    return big ? (hp - at) : at;
}

// packed variant: componentwise identical op sequence
__device__ __forceinline__ f32x2 fast_atan_ratio2(f32x2 v, f32x2 c, f32x2 rvv)
{
    const f32x2 rc = mk2(__builtin_amdgcn_rcpf(c.x), __builtin_amdgcn_rcpf(c.y));
    const f32x2 q  = v * rc;
    const f32x2 iq = c * rvv;
    const bool big0 = fabsf(q.x) > 1.0f, big1 = fabsf(q.y) > 1.0f;
    const f32x2 t = mk2(big0 ? iq.x : q.x, big1 ? iq.y : q.y);
    const f32x2 s = t * t;
    f32x2 p = fma2(s, sp2(-0.01172120f), sp2(0.05265332f));
    p = fma2(s, p, sp2(-0.11643287f));
    p = fma2(s, p, sp2( 0.19354346f));
    p = fma2(s, p, sp2(-0.33262347f));
    p = fma2(s, p, sp2( 0.99997726f));
    const f32x2 at = p * t;
    const float hp0 = copysignf(1.57079632679f, q.x);
    const float hp1 = copysignf(1.57079632679f, q.y);
    return mk2(big0 ? (hp0 - at.x) : at.x, big1 ? (hp1 - at.y) : at.y);
}

// Load the 6-wide window (cols j0-2..j0+3) of one row as 3 aligned float2.
// XE blocks: clamp wing addresses in-bounds, then substitute values:
//   left  (j0==0):     cols -2,-1 clamp to col 0      -> {c.x, c.x}
//   right (j0+2==Wn):  cols Wn,Wn+1 mirror to Wn-1..  -> {c.y, c.x}
template<bool XE>
__device__ __forceinline__ void load6(const float* __restrict__ rowp, int j0,
                                      bool left, bool right,
                                      f32x2& m, f32x2& c, f32x2& p)
{
    c = *reinterpret_cast<const f32x2*>(rowp + j0);
    if (XE) {
        const float* ma = rowp + (left  ? j0 : j0 - 2);
        const float* pa = rowp + (right ? j0 : j0 + 2);
        m = *reinterpret_cast<const f32x2*>(ma);
        p = *reinterpret_cast<const f32x2*>(pa);
        if (left)  m = mk2(c.x, c.x);
        if (right) p = mk2(c.y, c.x);
    } else {
        m = *reinterpret_cast<const f32x2*>(rowp + j0 - 2);
        p = *reinterpret_cast<const f32x2*>(rowp + j0 + 2);
    }
}

// Packed interior-Y strip with eps_x chain. Rows i0..i0+ROWS_PER-1,
// cols {j0, j0+1}. Carried state:
//   Bm,Bp (wings row i-1), Cm,Cc,Cp (i), Dm,Dc,Dp (i+1), Em,Ec,Ep (i+2)
//   xm1,x0,xp1 = eps_x(i-1 / i / i+1);  gc0,gc1 = raw center diffs rows i,i+1
template<bool XE>
__device__ __forceinline__ f32x2 strip_packed(
    const float* __restrict__ eps, int Wn, int i0, int j0,
    bool left, bool right, float rd2, f32x2 syjv, f32x2 symv)
{
    const f32x2 SC2    = sp2(1e-12f);
    const float FLOORV = (float)(1e-32 / 6.0);
    const float pi_d   = 3.14159265358979323846f / 1.1f;
    const f32x2 rd2v   = sp2(rd2);
    const f32x2 sxy    = syjv * rd2;     // exy scale (loop-invariant)

    const float* r0 = eps + (size_t)(i0 - 2) * (size_t)Wn;
    const f32x2 Ac = *reinterpret_cast<const f32x2*>(r0 + j0);
    f32x2 Bm, Bc, Bp, Cm, Cc, Cp, Dm, Dc, Dp, Em, Ec, Ep;
    load6<XE>(r0 + (size_t)Wn,     j0, left, right, Bm, Bc, Bp);
    load6<XE>(r0 + (size_t)2 * Wn, j0, left, right, Cm, Cc, Cp);
    load6<XE>(r0 + (size_t)3 * Wn, j0, left, right, Dm, Dc, Dp);
    load6<XE>(r0 + (size_t)4 * Wn, j0, left, right, Em, Ec, Ep);
    const float* pr = r0 + (size_t)5 * Wn;   // row i0+3

    // chain init (bit-identical to R9's exn/ex/exs formulas)
    f32x2 xm1 = fma2(Cc - Ac, rd2v, SC2);    // eps_x(i0-1)
    f32x2 gc0 = Dc - Bc;                     // raw diff row i0
    f32x2 x0  = fma2(gc0, rd2v, SC2);        // eps_x(i0)
    f32x2 gc1 = Ec - Cc;                     // raw diff row i0+1
    f32x2 xp1 = fma2(gc1, rd2v, SC2);        // eps_x(i0+1)

    f32x2 acc = sp2(0.0f);
    #pragma unroll 4
    for (int r = 0; r < ROWS_PER; ++r) {
        // prefetch row i+3 (3 independent float2 loads) before the compute
        f32x2 Fm, Fc, Fp;
        load6<XE>(pr, j0, left, right, Fm, Fc, Fp);
        pr += Wn;

        const f32x2 gc2 = Fc - Dc;               // raw diff row i+2
        const f32x2 x2v = fma2(gc2, rd2v, SC2);  // eps_x(i+2)

        const f32x2 ex  = x0;
        const f32x2 exx = (xp1 - xm1) * rd2;
        const f32x2 Cl1 = mk2(Cm.y, Cc.x), Cr1 = mk2(Cc.y, Cp.x);
        const f32x2 ey  = fma2(Cr1 - Cl1, syjv, SC2);
        f32x2 eyw = fma2(Cc - Cm, symv, SC2);
        const f32x2 eye = fma2(Cp - Cc, rd2v, SC2);
        if (XE) { if (left) eyw.x = ey.x; }       // j==0: eps_y[jm]==eps_y[j]
        const f32x2 eyy = (eye - eyw) * syjv;
        const f32x2 Gm = Dm - Bm, Gp = Dp - Bp;   // wing diffs row i
        const f32x2 exyL = mk2(Gm.y, gc0.x), exyR = mk2(gc0.y, Gp.x);
        const f32x2 exy = (exyR - exyL) * sxy;

        const f32x2 t1 = ex * ex, t2 = ey * ey;
        f32x2 num = t1 * eyy;
        num = fma2(t2, exx, num);
        num = fma2((ex * ey) * -2.0f, exy, num);
        const f32x2 ssum = t1 + t2;
        float ev0 = __builtin_amdgcn_sqrtf(ssum.x);
        float ev1 = __builtin_amdgcn_sqrtf(ssum.y);
        ev0 = fmaxf(ev0, FLOORV);
        ev1 = fmaxf(ev1, FLOORV);
        const f32x2 evv = mk2(ev0, ev1);
        const f32x2 rvv = mk2(__builtin_amdgcn_rcpf(ev0), __builtin_amdgcn_rcpf(ev1));
        const f32x2 k   = num * (rvv * rvv) * rvv;
        const f32x2 at  = fast_atan_ratio2(evv, Cc, rvv);
        const f32x2 cc  = abs2(k * at) - sp2(pi_d);
        acc = acc + max2(cc, sp2(0.0f));          // maxnum(NaN,0)=0 -> nansum

        // rotate (named registers; unroll-4 => renaming, few real movs)
        xm1 = x0; x0 = xp1; xp1 = x2v; gc0 = gc1; gc1 = gc2;
        Bm = Cm; Bp = Cp;
        Cm = Dm; Cc = Dc; Cp = Dp;
        Dm = Em; Dc = Ec; Dp = Ep;
        Em = Fm; Ec = Fc; Ep = Fp;
    }
    (void)Bc;
    return acc;
}

// R8's verified scalar Y-boundary strip (YB hardwired true), one column.
__device__ float strip_scalar_yb(const float* __restrict__ eps, int Hn, int Wn,
                                 int i0, int j, float rd, float rd2)
{
    const float SC     = 1e-12f;
    const float FLOORV = (float)(1e-32 / 6.0);
    const float pi_d   = 3.14159265358979323846f / 1.1f;

    const int jm  = (j > 0) ? j - 1 : 0;
    const int jmm = (j > 1) ? j - 2 : 0;
    const int jp = j + 1, jpp = j + 2;
    const int cjp  = (jp  < Wn) ? jp  : (2 * Wn - 1 - jp);
    const int cjpp = (jpp < Wn) ? jpp : (2 * Wn - 1 - jpp);
    const bool jz = (j == 0);
    const float syj = jz ? rd : rd2;
    const float sym = (jm == 0) ? rd : rd2;

    auto rp = [&](int t) -> const float* {
        int tt = t < 0 ? 0 : t;
        tt = tt > Hn - 1 ? Hn - 1 : tt;
        return eps + (size_t)tt * (size_t)Wn;
    };

    float a2 = rp(i0 - 2)[j],   a1 = rp(i0 - 1)[j],  a0 = rp(i0)[j];
    float b1 = rp(i0 + 1)[j],   b2 = rp(i0 + 2)[j];
    float wN = rp(i0 - 1)[jm],  w0 = rp(i0)[jm],     wS = rp(i0 + 1)[jm];
    float eN = rp(i0 - 1)[cjp], e0 = rp(i0)[cjp],    eS = rp(i0 + 1)[cjp];
    float ww = rp(i0)[jmm],     ee = rp(i0)[cjpp];

    float acc = 0.0f;
    #pragma unroll 4
    for (int r = 0; r < ROWS_PER; ++r) {
        const int i = i0 + r;
        const float* q3 = rp(i + 3);
        const float* q2 = rp(i + 2);
        const float* q1 = rp(i + 1);
        const float nb2 = q3[j], nwS = q2[jm], neS = q2[cjp];
        const float nww = q1[jmm], nee = q1[cjpp];

        const bool itop = (i == 0), ibot = (i == Hn - 1);
        const float sxi = (itop || ibot) ? rd : rd2;
        const float sxm = (i == 1) ? rd : rd2;
        const float sxp = (i == Hn - 2) ? rd : rd2;

        const float ex = fmaf(b1 - a1, sxi, SC);
        const float ey = fmaf(e0 - w0, syj, SC);
        float exn = fmaf(a0 - a2, sxm, SC);
        float exs = fmaf(b2 - a0, sxp, SC);
        if (itop) exn = ex;
        if (ibot) exs = ex;
        const float exx = (exs - exn) * sxi;
        float eyw = fmaf(a0 - ww, sym, SC);
        const float eye = fmaf(ee - a0, rd2, SC);
        if (jz) eyw = ey;
        const float eyy = (eye - eyw) * syj;
        const float exy = ((eS - eN) - (wS - wN)) * (sxi * syj);

        const float t1 = ex * ex, t2 = ey * ey;
        float num = t1 * eyy;
        num = fmaf(t2, exx, num);
        num = fmaf(-2.0f * (ex * ey), exy, num);
        float ev = __builtin_amdgcn_sqrtf(t1 + t2);
        ev = fmaxf(ev, FLOORV);
        const float rv = __builtin_amdgcn_rcpf(ev);
        const float k  = num * (rv * rv) * rv;
        const float at = fast_atan_ratio(ev, a0, rv);
        const float ccv = fabsf(k * at) - pi_d;
        float contrib = fmaxf(ccv, 0.0f);
        if (i >= Hn) contrib = 0.0f;
        acc += contrib;

        a2 = a1; a1 = a0; a0 = b1; b1 = b2; b2 = nb2;
        wN = w0; w0 = wS; wS = nwS;
        eN = e0; e0 = eS; eS = neS;
        ww = nww; ee = nee;
    }
    return acc;
}

__global__ __launch_bounds__(BLOCK_X, 4) void curve_partial_kernel(
    const float* __restrict__ eps, const float* __restrict__ gs,
    double* __restrict__ partial, float* __restrict__ out,
    int Hn, int Wn, int nb)
{
    const int tx = threadIdx.x;
    const int j0 = (blockIdx.x * BLOCK_X + tx) * 2;
    const int i0 = blockIdx.y * ROWS_PER;
    const float d   = gs[0];
    const float rd  = 1.0f / d;
    const float rd2 = 0.5f * rd;
    const bool left  = (j0 == 0);
    const bool right = (j0 + 2 == Wn);

    // interior path touches rows i0-2 .. i0+ROWS_PER+2 (incl. last prefetch)
    const bool yint = (i0 >= 2) && (i0 + ROWS_PER + 2 < Hn);

    f32x2 accv;
    if (yint) {
        const f32x2 syjv = left ? mk2(rd,  rd2) : sp2(rd2);  // col0: fwd diff
        const f32x2 symv = left ? mk2(rd2, rd ) : sp2(rd2);  // col1: jm==0
        const bool xe = (blockIdx.x == 0) || (blockIdx.x == gridDim.x - 1);
        accv = xe
            ? strip_packed<true >(eps, Wn, i0, j0, left, right, rd2, syjv, symv)
            : strip_packed<false>(eps, Wn, i0, j0, left, right, rd2, syjv, symv);
    } else {
        accv.x = strip_scalar_yb(eps, Hn, Wn, i0, j0,     rd, rd2);
        accv.y = strip_scalar_yb(eps, Hn, Wn, i0, j0 + 1, rd, rd2);
    }

    double acc = (double)accv.x + (double)accv.y;
    #pragma unroll
    for (int off = 32; off > 0; off >>= 1)
        acc += __shfl_down(acc, off, 64);
    __shared__ double lds[BLOCK_X / 64];
    __shared__ int elected;
    const int lane = tx & 63, wv = tx >> 6;
    if (lane == 0) lds[wv] = acc;
    __syncthreads();

    const int bid = blockIdx.y * gridDim.x + blockIdx.x;
    if (tx == 0) {
        const double bsum = lds[0] + lds[1] + lds[2] + lds[3];
        partial[bid] = bsum;          // plain store (no f64 atomics — R2/R3)
        __threadfence();              // release: make store device-visible
        const unsigned old = atomicAdd(&g_count, 1u);
        elected = (old == (unsigned)nb - 1u) ? 1 : 0;
    }
    __syncthreads();

    if (elected) {
        __threadfence();              // acquire side
        // bit-identical replay of the old finish kernel's reduction
        double a2 = 0.0;
        for (int idx = tx; idx < nb; idx += BLOCK_X) a2 += partial[idx];
        #pragma unroll
        for (int off = 32; off > 0; off >>= 1)
            a2 += __shfl_down(a2, off, 64);
        __syncthreads();              // lds reuse barrier
        if (lane == 0) lds[wv] = a2;
        __syncthreads();
        if (tx == 0) {
            const double dd = (double)gs[0];
            // x2 for the mirrored half; x d^2 for grid_size^2 (ALPHA=1)
            out[0] = (float)((lds[0] + lds[1] + lds[2] + lds[3]) * 2.0 * dd * dd);
            atomicExch(&g_count, 0u);   // self-reset for the next replay
        }
    }
}

extern "C" void kernel_launch(void* const* d_in, const int* in_sizes, int n_in,
                              void* d_out, int out_size, void* d_ws, size_t ws_size,
                              hipStream_t stream) {
    const float* eps = (const float*)d_in[0];
    const float* gs  = (const float*)d_in[1];
    float* out = (float*)d_out;

    const int n = in_sizes[0];
    int Wn = (int)(sqrt((double)n) + 0.5);   // 4096 for 4096x4096
    int Hn = n / Wn;

    const int gx = Wn / (BLOCK_X * 2);               // 8 (assumes divisible)
    const int gy = (Hn + ROWS_PER - 1) / ROWS_PER;   // 256
    const int nb = gx * gy;                          // 2048
    double* partial = (double*)d_ws;   // nb slots, ALL written every launch

    curve_partial_kernel<<<dim3(gx, gy), BLOCK_X, 0, stream>>>(
        eps, gs, partial, out, Hn, Wn, nb);
}

// Round 8
// 110.005 us; speedup vs baseline: 1.4384x; 1.4384x over previous
//
#include <hip/hip_runtime.h>
#include <math.h>

// fab_penalty_ls_curve — R11: R10's eps_x-chain compute + R9b's two-kernel
// finish. R10 post-mortem: the fused last-block finish regressed partial
// 38->91-114us (VALUBusy 14%, high variance) — per-block device-scope
// __threadfence must make stores visible across the 8 non-coherent per-XCD
// L2s (L2 wb/inv traffic) and 2048 same-address atomics serialize block
// retirement. THIRD confirmation (R2/R3, R10) that single-launch handshakes
// lose to two plain launches on MI355X. WRITE_SIZE stayed 128KB and VGPR 52
// => the eps_x chain itself didn't spill and is kept.
// Chain (bit-identical, absmax 0.0 verified in R10): exn/ex/exs at point i
// are eps_x(i-1..i+1) — 3-deep rolling chain, only eps_x(i+2) fresh; raw
// diff Fc-Dc doubles as future exy center diff; exy = (G[j+1]-G[j-1])*s.
// Spill tripwire: WRITE_SIZE must stay ~128KB. Assumes Wn % (2*BLOCK_X) == 0.

#define BLOCK_X 256
#define ROWS_PER 16

typedef float f32x2 __attribute__((ext_vector_type(2)));

__device__ __forceinline__ f32x2 mk2(float a, float b) { f32x2 v; v.x = a; v.y = b; return v; }
__device__ __forceinline__ f32x2 sp2(float a) { return mk2(a, a); }

#if __has_builtin(__builtin_elementwise_fma)
__device__ __forceinline__ f32x2 fma2(f32x2 a, f32x2 b, f32x2 c) { return __builtin_elementwise_fma(a, b, c); }
#else
__device__ __forceinline__ f32x2 fma2(f32x2 a, f32x2 b, f32x2 c) { return mk2(fmaf(a.x, b.x, c.x), fmaf(a.y, b.y, c.y)); }
#endif
#if __has_builtin(__builtin_elementwise_max)
__device__ __forceinline__ f32x2 max2(f32x2 a, f32x2 b) { return __builtin_elementwise_max(a, b); }
#else
__device__ __forceinline__ f32x2 max2(f32x2 a, f32x2 b) { return mk2(fmaxf(a.x, b.x), fmaxf(a.y, b.y)); }
#endif
__device__ __forceinline__ f32x2 abs2(f32x2 a) { return mk2(fabsf(a.x), fabsf(a.y)); }

// ---- scalar helpers (YB path + per-component transcendentals) ----

// atan(v / c) with v > 0, given rv ~= 1/v. Max abs err ~1e-5 rad.
__device__ __forceinline__ float fast_atan_ratio(float v, float c, float rv)
{
    const float rc = __builtin_amdgcn_rcpf(c);
    const float q  = v * rc;
    const float iq = c * rv;
    const bool  big = fabsf(q) > 1.0f;
    const float t  = big ? iq : q;
    const float s  = t * t;
    float p = fmaf(s, -0.01172120f, 0.05265332f);
    p = fmaf(s, p, -0.11643287f);
    p = fmaf(s, p,  0.19354346f);
    p = fmaf(s, p, -0.33262347f);
    p = fmaf(s, p,  0.99997726f);
    const float at = p * t;
    const float hp = copysignf(1.57079632679f, q);
    return big ? (hp - at) : at;
}

// packed variant: componentwise identical op sequence
__device__ __forceinline__ f32x2 fast_atan_ratio2(f32x2 v, f32x2 c, f32x2 rvv)
{
    const f32x2 rc = mk2(__builtin_amdgcn_rcpf(c.x), __builtin_amdgcn_rcpf(c.y));
    const f32x2 q  = v * rc;
    const f32x2 iq = c * rvv;
    const bool big0 = fabsf(q.x) > 1.0f, big1 = fabsf(q.y) > 1.0f;
    const f32x2 t = mk2(big0 ? iq.x : q.x, big1 ? iq.y : q.y);
    const f32x2 s = t * t;
    f32x2 p = fma2(s, sp2(-0.01172120f), sp2(0.05265332f));
    p = fma2(s, p, sp2(-0.11643287f));
    p = fma2(s, p, sp2( 0.19354346f));
    p = fma2(s, p, sp2(-0.33262347f));
    p = fma2(s, p, sp2( 0.99997726f));
    const f32x2 at = p * t;
    const float hp0 = copysignf(1.57079632679f, q.x);
    const float hp1 = copysignf(1.57079632679f, q.y);
    return mk2(big0 ? (hp0 - at.x) : at.x, big1 ? (hp1 - at.y) : at.y);
}

// Load the 6-wide window (cols j0-2..j0+3) of one row as 3 aligned float2.
// XE blocks: clamp wing addresses in-bounds, then substitute values:
//   left  (j0==0):     cols -2,-1 clamp to col 0      -> {c.x, c.x}
//   right (j0+2==Wn):  cols Wn,Wn+1 mirror to Wn-1..  -> {c.y, c.x}
template<bool XE>
__device__ __forceinline__ void load6(const float* __restrict__ rowp, int j0,
                                      bool left, bool right,
                                      f32x2& m, f32x2& c, f32x2& p)
{
    c = *reinterpret_cast<const f32x2*>(rowp + j0);
    if (XE) {
        const float* ma = rowp + (left  ? j0 : j0 - 2);
        const float* pa = rowp + (right ? j0 : j0 + 2);
        m = *reinterpret_cast<const f32x2*>(ma);
        p = *reinterpret_cast<const f32x2*>(pa);
        if (left)  m = mk2(c.x, c.x);
        if (right) p = mk2(c.y, c.x);
    } else {
        m = *reinterpret_cast<const f32x2*>(rowp + j0 - 2);
        p = *reinterpret_cast<const f32x2*>(rowp + j0 + 2);
    }
}

// Packed interior-Y strip with eps_x chain. Rows i0..i0+ROWS_PER-1,
// cols {j0, j0+1}. Carried state:
//   Bm,Bp (wings row i-1), Cm,Cc,Cp (i), Dm,Dc,Dp (i+1), Em,Ec,Ep (i+2)
//   xm1,x0,xp1 = eps_x(i-1 / i / i+1);  gc0,gc1 = raw center diffs rows i,i+1
template<bool XE>
__device__ __forceinline__ f32x2 strip_packed(
    const float* __restrict__ eps, int Wn, int i0, int j0,
    bool left, bool right, float rd2, f32x2 syjv, f32x2 symv)
{
    const f32x2 SC2    = sp2(1e-12f);
    const float FLOORV = (float)(1e-32 / 6.0);
    const float pi_d   = 3.14159265358979323846f / 1.1f;
    const f32x2 rd2v   = sp2(rd2);
    const f32x2 sxy    = syjv * rd2;     // exy scale (loop-invariant)

    const float* r0 = eps + (size_t)(i0 - 2) * (size_t)Wn;
    const f32x2 Ac = *reinterpret_cast<const f32x2*>(r0 + j0);
    f32x2 Bm, Bc, Bp, Cm, Cc, Cp, Dm, Dc, Dp, Em, Ec, Ep;
    load6<XE>(r0 + (size_t)Wn,     j0, left, right, Bm, Bc, Bp);
    load6<XE>(r0 + (size_t)2 * Wn, j0, left, right, Cm, Cc, Cp);
    load6<XE>(r0 + (size_t)3 * Wn, j0, left, right, Dm, Dc, Dp);
    load6<XE>(r0 + (size_t)4 * Wn, j0, left, right, Em, Ec, Ep);
    const float* pr = r0 + (size_t)5 * Wn;   // row i0+3

    // chain init (bit-identical to R9's exn/ex/exs formulas)
    f32x2 xm1 = fma2(Cc - Ac, rd2v, SC2);    // eps_x(i0-1)
    f32x2 gc0 = Dc - Bc;                     // raw diff row i0
    f32x2 x0  = fma2(gc0, rd2v, SC2);        // eps_x(i0)
    f32x2 gc1 = Ec - Cc;                     // raw diff row i0+1
    f32x2 xp1 = fma2(gc1, rd2v, SC2);        // eps_x(i0+1)

    f32x2 acc = sp2(0.0f);
    #pragma unroll 4
    for (int r = 0; r < ROWS_PER; ++r) {
        // prefetch row i+3 (3 independent float2 loads) before the compute
        f32x2 Fm, Fc, Fp;
        load6<XE>(pr, j0, left, right, Fm, Fc, Fp);
        pr += Wn;

        const f32x2 gc2 = Fc - Dc;               // raw diff row i+2
        const f32x2 x2v = fma2(gc2, rd2v, SC2);  // eps_x(i+2)

        const f32x2 ex  = x0;
        const f32x2 exx = (xp1 - xm1) * rd2;
        const f32x2 Cl1 = mk2(Cm.y, Cc.x), Cr1 = mk2(Cc.y, Cp.x);
        const f32x2 ey  = fma2(Cr1 - Cl1, syjv, SC2);
        f32x2 eyw = fma2(Cc - Cm, symv, SC2);
        const f32x2 eye = fma2(Cp - Cc, rd2v, SC2);
        if (XE) { if (left) eyw.x = ey.x; }       // j==0: eps_y[jm]==eps_y[j]
        const f32x2 eyy = (eye - eyw) * syjv;
        const f32x2 Gm = Dm - Bm, Gp = Dp - Bp;   // wing diffs row i
        const f32x2 exyL = mk2(Gm.y, gc0.x), exyR = mk2(gc0.y, Gp.x);
        const f32x2 exy = (exyR - exyL) * sxy;

        const f32x2 t1 = ex * ex, t2 = ey * ey;
        f32x2 num = t1 * eyy;
        num = fma2(t2, exx, num);
        num = fma2((ex * ey) * -2.0f, exy, num);
        const f32x2 ssum = t1 + t2;
        float ev0 = __builtin_amdgcn_sqrtf(ssum.x);
        float ev1 = __builtin_amdgcn_sqrtf(ssum.y);
        ev0 = fmaxf(ev0, FLOORV);
        ev1 = fmaxf(ev1, FLOORV);
        const f32x2 evv = mk2(ev0, ev1);
        const f32x2 rvv = mk2(__builtin_amdgcn_rcpf(ev0), __builtin_amdgcn_rcpf(ev1));
        const f32x2 k   = num * (rvv * rvv) * rvv;
        const f32x2 at  = fast_atan_ratio2(evv, Cc, rvv);
        const f32x2 cc  = abs2(k * at) - sp2(pi_d);
        acc = acc + max2(cc, sp2(0.0f));          // maxnum(NaN,0)=0 -> nansum

        // rotate (named registers; unroll-4 => renaming, few real movs)
        xm1 = x0; x0 = xp1; xp1 = x2v; gc0 = gc1; gc1 = gc2;
        Bm = Cm; Bp = Cp;
        Cm = Dm; Cc = Dc; Cp = Dp;
        Dm = Em; Dc = Ec; Dp = Ep;
        Em = Fm; Ec = Fc; Ep = Fp;
    }
    (void)Bc;
    return acc;
}

// R8's verified scalar Y-boundary strip (YB hardwired true), one column.
__device__ float strip_scalar_yb(const float* __restrict__ eps, int Hn, int Wn,
                                 int i0, int j, float rd, float rd2)
{
    const float SC     = 1e-12f;
    const float FLOORV = (float)(1e-32 / 6.0);
    const float pi_d   = 3.14159265358979323846f / 1.1f;

    const int jm  = (j > 0) ? j - 1 : 0;
    const int jmm = (j > 1) ? j - 2 : 0;
    const int jp = j + 1, jpp = j + 2;
    const int cjp  = (jp  < Wn) ? jp  : (2 * Wn - 1 - jp);
    const int cjpp = (jpp < Wn) ? jpp : (2 * Wn - 1 - jpp);
    const bool jz = (j == 0);
    const float syj = jz ? rd : rd2;
    const float sym = (jm == 0) ? rd : rd2;

    auto rp = [&](int t) -> const float* {
        int tt = t < 0 ? 0 : t;
        tt = tt > Hn - 1 ? Hn - 1 : tt;
        return eps + (size_t)tt * (size_t)Wn;
    };

    float a2 = rp(i0 - 2)[j],   a1 = rp(i0 - 1)[j],  a0 = rp(i0)[j];
    float b1 = rp(i0 + 1)[j],   b2 = rp(i0 + 2)[j];
    float wN = rp(i0 - 1)[jm],  w0 = rp(i0)[jm],     wS = rp(i0 + 1)[jm];
    float eN = rp(i0 - 1)[cjp], e0 = rp(i0)[cjp],    eS = rp(i0 + 1)[cjp];
    float ww = rp(i0)[jmm],     ee = rp(i0)[cjpp];

    float acc = 0.0f;
    #pragma unroll 4
    for (int r = 0; r < ROWS_PER; ++r) {
        const int i = i0 + r;
        const float* q3 = rp(i + 3);
        const float* q2 = rp(i + 2);
        const float* q1 = rp(i + 1);
        const float nb2 = q3[j], nwS = q2[jm], neS = q2[cjp];
        const float nww = q1[jmm], nee = q1[cjpp];

        const bool itop = (i == 0), ibot = (i == Hn - 1);
        const float sxi = (itop || ibot) ? rd : rd2;
        const float sxm = (i == 1) ? rd : rd2;
        const float sxp = (i == Hn - 2) ? rd : rd2;

        const float ex = fmaf(b1 - a1, sxi, SC);
        const float ey = fmaf(e0 - w0, syj, SC);
        float exn = fmaf(a0 - a2, sxm, SC);
        float exs = fmaf(b2 - a0, sxp, SC);
        if (itop) exn = ex;
        if (ibot) exs = ex;
        const float exx = (exs - exn) * sxi;
        float eyw = fmaf(a0 - ww, sym, SC);
        const float eye = fmaf(ee - a0, rd2, SC);
        if (jz) eyw = ey;
        const float eyy = (eye - eyw) * syj;
        const float exy = ((eS - eN) - (wS - wN)) * (sxi * syj);

        const float t1 = ex * ex, t2 = ey * ey;
        float num = t1 * eyy;
        num = fmaf(t2, exx, num);
        num = fmaf(-2.0f * (ex * ey), exy, num);
        float ev = __builtin_amdgcn_sqrtf(t1 + t2);
        ev = fmaxf(ev, FLOORV);
        const float rv = __builtin_amdgcn_rcpf(ev);
        const float k  = num * (rv * rv) * rv;
        const float at = fast_atan_ratio(ev, a0, rv);
        const float ccv = fabsf(k * at) - pi_d;
        float contrib = fmaxf(ccv, 0.0f);
        if (i >= Hn) contrib = 0.0f;
        acc += contrib;

        a2 = a1; a1 = a0; a0 = b1; b1 = b2; b2 = nb2;
        wN = w0; w0 = wS; wS = nwS;
        eN = e0; e0 = eS; eS = neS;
        ww = nww; ee = nee;
    }
    return acc;
}

__global__ __launch_bounds__(BLOCK_X, 4) void curve_partial_kernel(
    const float* __restrict__ eps, const float* __restrict__ gs,
    double* __restrict__ partial, int Hn, int Wn)
{
    const int tx = threadIdx.x;
    const int j0 = (blockIdx.x * BLOCK_X + tx) * 2;
    const int i0 = blockIdx.y * ROWS_PER;
    const float d   = gs[0];
    const float rd  = 1.0f / d;
    const float rd2 = 0.5f * rd;
    const bool left  = (j0 == 0);
    const bool right = (j0 + 2 == Wn);

    // interior path touches rows i0-2 .. i0+ROWS_PER+2 (incl. last prefetch)
    const bool yint = (i0 >= 2) && (i0 + ROWS_PER + 2 < Hn);

    f32x2 accv;
    if (yint) {
        const f32x2 syjv = left ? mk2(rd,  rd2) : sp2(rd2);  // col0: fwd diff
        const f32x2 symv = left ? mk2(rd2, rd ) : sp2(rd2);  // col1: jm==0
        const bool xe = (blockIdx.x == 0) || (blockIdx.x == gridDim.x - 1);
        accv = xe
            ? strip_packed<true >(eps, Wn, i0, j0, left, right, rd2, syjv, symv)
            : strip_packed<false>(eps, Wn, i0, j0, left, right, rd2, syjv, symv);
    } else {
        accv.x = strip_scalar_yb(eps, Hn, Wn, i0, j0,     rd, rd2);
        accv.y = strip_scalar_yb(eps, Hn, Wn, i0, j0 + 1, rd, rd2);
    }

    double acc = (double)accv.x + (double)accv.y;
    #pragma unroll
    for (int off = 32; off > 0; off >>= 1)
        acc += __shfl_down(acc, off, 64);
    __shared__ double lds[BLOCK_X / 64];
    const int lane = tx & 63, wv = tx >> 6;
    if (lane == 0) lds[wv] = acc;
    __syncthreads();
    if (tx == 0) {
        // plain store — NO device-scope atomics/fences (R2/R3/R10 regressions)
        partial[blockIdx.y * gridDim.x + blockIdx.x] =
            lds[0] + lds[1] + lds[2] + lds[3];
    }
}

__global__ __launch_bounds__(256) void curve_finish_kernel(
    const double* __restrict__ partial, int n,
    const float* __restrict__ gs, float* __restrict__ out)
{
    const int tx = threadIdx.x;
    double acc = 0.0;
    for (int idx = tx; idx < n; idx += 256) acc += partial[idx];
    #pragma unroll
    for (int off = 32; off > 0; off >>= 1)
        acc += __shfl_down(acc, off, 64);
    __shared__ double lds[4];
    const int lane = tx & 63, wv = tx >> 6;
    if (lane == 0) lds[wv] = acc;
    __syncthreads();
    if (tx == 0) {
        const double dd = (double)gs[0];
        // x2 for the mirrored half; x d^2 for grid_size^2 (ALPHA=1)
        out[0] = (float)((lds[0] + lds[1] + lds[2] + lds[3]) * 2.0 * dd * dd);
    }
}

extern "C" void kernel_launch(void* const* d_in, const int* in_sizes, int n_in,
                              void* d_out, int out_size, void* d_ws, size_t ws_size,
                              hipStream_t stream) {
    const float* eps = (const float*)d_in[0];
    const float* gs  = (const float*)d_in[1];
    float* out = (float*)d_out;

    const int n = in_sizes[0];
    int Wn = (int)(sqrt((double)n) + 0.5);   // 4096 for 4096x4096
    int Hn = n / Wn;

    const int gx = Wn / (BLOCK_X * 2);               // 8 (assumes divisible)
    const int gy = (Hn + ROWS_PER - 1) / ROWS_PER;   // 256
    const int nb = gx * gy;                          // 2048
    double* partial = (double*)d_ws;   // nb slots, ALL written every launch

    curve_partial_kernel<<<dim3(gx, gy), BLOCK_X, 0, stream>>>(eps, gs, partial, Hn, Wn);
    curve_finish_kernel<<<1, 256, 0, stream>>>(partial, nb, gs, out);
}

// Round 9
// 108.391 us; speedup vs baseline: 1.4599x; 1.0149x over previous
//
#include <hip/hip_runtime.h>
#include <math.h>

// fab_penalty_ls_curve — R12: R11 + rsqrt merge + ROWS_PER 32 + packed floor.
// R11 post-mortem (confirmed): total 110.0us best; partial ~35.7us (fixed
// overhead stable at 74.2us across R8/R9b/R11: 41us harness workspace fill
// + finish + launch gaps). Two-kernel plain-store reduction is settled law
// on MI355X (R2/R3, R10: device-scope handshakes regress 2-3x).
// R12 cuts (additive, low-risk):
// (1) rsqrt merge: rv = v_rsq(ssum), ev = ssum*rv — replaces sqrt+rcp
//     (2 quarter-rate trans -> 1 trans + 1 mul), ~4 issue-slots/point.
//     ONLY numerics change this round (~1e-7 rel on rv/ev, 100x below the
//     accepted fast-atan error). ssum==0 corner: rs=inf -> ev=NaN ->
//     maxnum(NaN,FLOOR)=FLOOR -> k=0*inf=NaN -> max(NaN,0)=0, same as old.
// (2) ROWS_PER 16->32: halves prologue amortization, blocks 2048->1024.
// (3) max2 packed floor (v_pk_max_f32, bit-identical maxnum).
// NOT doing 4-col f32x4: ~90-110 VGPR -> 4 waves/SIMD occupancy cliff (R5).
// Spill tripwire: WRITE_SIZE must stay ~128KB. Assumes Wn % (2*BLOCK_X) == 0.

#define BLOCK_X 256
#define ROWS_PER 32

typedef float f32x2 __attribute__((ext_vector_type(2)));

__device__ __forceinline__ f32x2 mk2(float a, float b) { f32x2 v; v.x = a; v.y = b; return v; }
__device__ __forceinline__ f32x2 sp2(float a) { return mk2(a, a); }

#if __has_builtin(__builtin_elementwise_fma)
__device__ __forceinline__ f32x2 fma2(f32x2 a, f32x2 b, f32x2 c) { return __builtin_elementwise_fma(a, b, c); }
#else
__device__ __forceinline__ f32x2 fma2(f32x2 a, f32x2 b, f32x2 c) { return mk2(fmaf(a.x, b.x, c.x), fmaf(a.y, b.y, c.y)); }
#endif
#if __has_builtin(__builtin_elementwise_max)
__device__ __forceinline__ f32x2 max2(f32x2 a, f32x2 b) { return __builtin_elementwise_max(a, b); }
#else
__device__ __forceinline__ f32x2 max2(f32x2 a, f32x2 b) { return mk2(fmaxf(a.x, b.x), fmaxf(a.y, b.y)); }
#endif
__device__ __forceinline__ f32x2 abs2(f32x2 a) { return mk2(fabsf(a.x), fabsf(a.y)); }

// ---- scalar helpers (YB path + per-component transcendentals) ----

// atan(v / c) with v > 0, given rv ~= 1/v. Max abs err ~1e-5 rad.
__device__ __forceinline__ float fast_atan_ratio(float v, float c, float rv)
{
    const float rc = __builtin_amdgcn_rcpf(c);
    const float q  = v * rc;
    const float iq = c * rv;
    const bool  big = fabsf(q) > 1.0f;
    const float t  = big ? iq : q;
    const float s  = t * t;
    float p = fmaf(s, -0.01172120f, 0.05265332f);
    p = fmaf(s, p, -0.11643287f);
    p = fmaf(s, p,  0.19354346f);
    p = fmaf(s, p, -0.33262347f);
    p = fmaf(s, p,  0.99997726f);
    const float at = p * t;
    const float hp = copysignf(1.57079632679f, q);
    return big ? (hp - at) : at;
}

// packed variant: componentwise identical op sequence
__device__ __forceinline__ f32x2 fast_atan_ratio2(f32x2 v, f32x2 c, f32x2 rvv)
{
    const f32x2 rc = mk2(__builtin_amdgcn_rcpf(c.x), __builtin_amdgcn_rcpf(c.y));
    const f32x2 q  = v * rc;
    const f32x2 iq = c * rvv;
    const bool big0 = fabsf(q.x) > 1.0f, big1 = fabsf(q.y) > 1.0f;
    const f32x2 t = mk2(big0 ? iq.x : q.x, big1 ? iq.y : q.y);
    const f32x2 s = t * t;
    f32x2 p = fma2(s, sp2(-0.01172120f), sp2(0.05265332f));
    p = fma2(s, p, sp2(-0.11643287f));
    p = fma2(s, p, sp2( 0.19354346f));
    p = fma2(s, p, sp2(-0.33262347f));
    p = fma2(s, p, sp2( 0.99997726f));
    const f32x2 at = p * t;
    const float hp0 = copysignf(1.57079632679f, q.x);
    const float hp1 = copysignf(1.57079632679f, q.y);
    return mk2(big0 ? (hp0 - at.x) : at.x, big1 ? (hp1 - at.y) : at.y);
}

// Load the 6-wide window (cols j0-2..j0+3) of one row as 3 aligned float2.
// XE blocks: clamp wing addresses in-bounds, then substitute values:
//   left  (j0==0):     cols -2,-1 clamp to col 0      -> {c.x, c.x}
//   right (j0+2==Wn):  cols Wn,Wn+1 mirror to Wn-1..  -> {c.y, c.x}
template<bool XE>
__device__ __forceinline__ void load6(const float* __restrict__ rowp, int j0,
                                      bool left, bool right,
                                      f32x2& m, f32x2& c, f32x2& p)
{
    c = *reinterpret_cast<const f32x2*>(rowp + j0);
    if (XE) {
        const float* ma = rowp + (left  ? j0 : j0 - 2);
        const float* pa = rowp + (right ? j0 : j0 + 2);
        m = *reinterpret_cast<const f32x2*>(ma);
        p = *reinterpret_cast<const f32x2*>(pa);
        if (left)  m = mk2(c.x, c.x);
        if (right) p = mk2(c.y, c.x);
    } else {
        m = *reinterpret_cast<const f32x2*>(rowp + j0 - 2);
        p = *reinterpret_cast<const f32x2*>(rowp + j0 + 2);
    }
}

// Packed interior-Y strip with eps_x chain. Rows i0..i0+ROWS_PER-1,
// cols {j0, j0+1}. Carried state:
//   Bm,Bp (wings row i-1), Cm,Cc,Cp (i), Dm,Dc,Dp (i+1), Em,Ec,Ep (i+2)
//   xm1,x0,xp1 = eps_x(i-1 / i / i+1);  gc0,gc1 = raw center diffs rows i,i+1
template<bool XE>
__device__ __forceinline__ f32x2 strip_packed(
    const float* __restrict__ eps, int Wn, int i0, int j0,
    bool left, bool right, float rd2, f32x2 syjv, f32x2 symv)
{
    const f32x2 SC2    = sp2(1e-12f);
    const float FLOORV = (float)(1e-32 / 6.0);
    const float pi_d   = 3.14159265358979323846f / 1.1f;
    const f32x2 rd2v   = sp2(rd2);
    const f32x2 sxy    = syjv * rd2;     // exy scale (loop-invariant)

    const float* r0 = eps + (size_t)(i0 - 2) * (size_t)Wn;
    const f32x2 Ac = *reinterpret_cast<const f32x2*>(r0 + j0);
    f32x2 Bm, Bc, Bp, Cm, Cc, Cp, Dm, Dc, Dp, Em, Ec, Ep;
    load6<XE>(r0 + (size_t)Wn,     j0, left, right, Bm, Bc, Bp);
    load6<XE>(r0 + (size_t)2 * Wn, j0, left, right, Cm, Cc, Cp);
    load6<XE>(r0 + (size_t)3 * Wn, j0, left, right, Dm, Dc, Dp);
    load6<XE>(r0 + (size_t)4 * Wn, j0, left, right, Em, Ec, Ep);
    const float* pr = r0 + (size_t)5 * Wn;   // row i0+3

    // chain init (bit-identical to R9's exn/ex/exs formulas)
    f32x2 xm1 = fma2(Cc - Ac, rd2v, SC2);    // eps_x(i0-1)
    f32x2 gc0 = Dc - Bc;                     // raw diff row i0
    f32x2 x0  = fma2(gc0, rd2v, SC2);        // eps_x(i0)
    f32x2 gc1 = Ec - Cc;                     // raw diff row i0+1
    f32x2 xp1 = fma2(gc1, rd2v, SC2);        // eps_x(i0+1)

    f32x2 acc = sp2(0.0f);
    #pragma unroll 4
    for (int r = 0; r < ROWS_PER; ++r) {
        // prefetch row i+3 (3 independent float2 loads) before the compute
        f32x2 Fm, Fc, Fp;
        load6<XE>(pr, j0, left, right, Fm, Fc, Fp);
        pr += Wn;

        const f32x2 gc2 = Fc - Dc;               // raw diff row i+2
        const f32x2 x2v = fma2(gc2, rd2v, SC2);  // eps_x(i+2)

        const f32x2 ex  = x0;
        const f32x2 exx = (xp1 - xm1) * rd2;
        const f32x2 Cl1 = mk2(Cm.y, Cc.x), Cr1 = mk2(Cc.y, Cp.x);
        const f32x2 ey  = fma2(Cr1 - Cl1, syjv, SC2);
        f32x2 eyw = fma2(Cc - Cm, symv, SC2);
        const f32x2 eye = fma2(Cp - Cc, rd2v, SC2);
        if (XE) { if (left) eyw.x = ey.x; }       // j==0: eps_y[jm]==eps_y[j]
        const f32x2 eyy = (eye - eyw) * syjv;
        const f32x2 Gm = Dm - Bm, Gp = Dp - Bp;   // wing diffs row i
        const f32x2 exyL = mk2(Gm.y, gc0.x), exyR = mk2(gc0.y, Gp.x);
        const f32x2 exy = (exyR - exyL) * sxy;

        const f32x2 t1 = ex * ex, t2 = ey * ey;
        f32x2 num = t1 * eyy;
        num = fma2(t2, exx, num);
        num = fma2((ex * ey) * -2.0f, exy, num);
        const f32x2 ssum = t1 + t2;
        // rsqrt merge: rv = rsq(ssum), ev = ssum*rv (saves one trans op)
        const f32x2 rvv = mk2(__builtin_amdgcn_rsqf(ssum.x),
                              __builtin_amdgcn_rsqf(ssum.y));
        f32x2 evv = ssum * rvv;
        evv = max2(evv, sp2(FLOORV));             // packed maxnum floor
        const f32x2 k   = num * (rvv * rvv) * rvv;
        const f32x2 at  = fast_atan_ratio2(evv, Cc, rvv);
        const f32x2 cc  = abs2(k * at) - sp2(pi_d);
        acc = acc + max2(cc, sp2(0.0f));          // maxnum(NaN,0)=0 -> nansum

        // rotate (named registers; unroll-4 => renaming, few real movs)
        xm1 = x0; x0 = xp1; xp1 = x2v; gc0 = gc1; gc1 = gc2;
        Bm = Cm; Bp = Cp;
        Cm = Dm; Cc = Dc; Cp = Dp;
        Dm = Em; Dc = Ec; Dp = Ep;
        Em = Fm; Ec = Fc; Ep = Fp;
    }
    (void)Bc;
    return acc;
}

// R8's verified scalar Y-boundary strip (YB hardwired true), one column.
__device__ float strip_scalar_yb(const float* __restrict__ eps, int Hn, int Wn,
                                 int i0, int j, float rd, float rd2)
{
    const float SC     = 1e-12f;
    const float FLOORV = (float)(1e-32 / 6.0);
    const float pi_d   = 3.14159265358979323846f / 1.1f;

    const int jm  = (j > 0) ? j - 1 : 0;
    const int jmm = (j > 1) ? j - 2 : 0;
    const int jp = j + 1, jpp = j + 2;
    const int cjp  = (jp  < Wn) ? jp  : (2 * Wn - 1 - jp);
    const int cjpp = (jpp < Wn) ? jpp : (2 * Wn - 1 - jpp);
    const bool jz = (j == 0);
    const float syj = jz ? rd : rd2;
    const float sym = (jm == 0) ? rd : rd2;

    auto rp = [&](int t) -> const float* {
        int tt = t < 0 ? 0 : t;
        tt = tt > Hn - 1 ? Hn - 1 : tt;
        return eps + (size_t)tt * (size_t)Wn;
    };

    float a2 = rp(i0 - 2)[j],   a1 = rp(i0 - 1)[j],  a0 = rp(i0)[j];
    float b1 = rp(i0 + 1)[j],   b2 = rp(i0 + 2)[j];
    float wN = rp(i0 - 1)[jm],  w0 = rp(i0)[jm],     wS = rp(i0 + 1)[jm];
    float eN = rp(i0 - 1)[cjp], e0 = rp(i0)[cjp],    eS = rp(i0 + 1)[cjp];
    float ww = rp(i0)[jmm],     ee = rp(i0)[cjpp];

    float acc = 0.0f;
    #pragma unroll 4
    for (int r = 0; r < ROWS_PER; ++r) {
        const int i = i0 + r;
        const float* q3 = rp(i + 3);
        const float* q2 = rp(i + 2);
        const float* q1 = rp(i + 1);
        const float nb2 = q3[j], nwS = q2[jm], neS = q2[cjp];
        const float nww = q1[jmm], nee = q1[cjpp];

        const bool itop = (i == 0), ibot = (i == Hn - 1);
        const float sxi = (itop || ibot) ? rd : rd2;
        const float sxm = (i == 1) ? rd : rd2;
        const float sxp = (i == Hn - 2) ? rd : rd2;

        const float ex = fmaf(b1 - a1, sxi, SC);
        const float ey = fmaf(e0 - w0, syj, SC);
        float exn = fmaf(a0 - a2, sxm, SC);
        float exs = fmaf(b2 - a0, sxp, SC);
        if (itop) exn = ex;
        if (ibot) exs = ex;
        const float exx = (exs - exn) * sxi;
        float eyw = fmaf(a0 - ww, sym, SC);
        const float eye = fmaf(ee - a0, rd2, SC);
        if (jz) eyw = ey;
        const float eyy = (eye - eyw) * syj;
        const float exy = ((eS - eN) - (wS - wN)) * (sxi * syj);

        const float t1 = ex * ex, t2 = ey * ey;
        float num = t1 * eyy;
        num = fmaf(t2, exx, num);
        num = fmaf(-2.0f * (ex * ey), exy, num);
        const float ssum = t1 + t2;
        // rsqrt merge (matches packed path)
        const float rv = __builtin_amdgcn_rsqf(ssum);
        float ev = ssum * rv;
        ev = fmaxf(ev, FLOORV);
        const float k  = num * (rv * rv) * rv;
        const float at = fast_atan_ratio(ev, a0, rv);
        const float ccv = fabsf(k * at) - pi_d;
        float contrib = fmaxf(ccv, 0.0f);
        if (i >= Hn) contrib = 0.0f;
        acc += contrib;

        a2 = a1; a1 = a0; a0 = b1; b1 = b2; b2 = nb2;
        wN = w0; w0 = wS; wS = nwS;
        eN = e0; e0 = eS; eS = neS;
        ww = nww; ee = nee;
    }
    return acc;
}

__global__ __launch_bounds__(BLOCK_X, 4) void curve_partial_kernel(
    const float* __restrict__ eps, const float* __restrict__ gs,
    double* __restrict__ partial, int Hn, int Wn)
{
    const int tx = threadIdx.x;
    const int j0 = (blockIdx.x * BLOCK_X + tx) * 2;
    const int i0 = blockIdx.y * ROWS_PER;
    const float d   = gs[0];
    const float rd  = 1.0f / d;
    const float rd2 = 0.5f * rd;
    const bool left  = (j0 == 0);
    const bool right = (j0 + 2 == Wn);

    // interior path touches rows i0-2 .. i0+ROWS_PER+2 (incl. last prefetch)
    const bool yint = (i0 >= 2) && (i0 + ROWS_PER + 2 < Hn);

    f32x2 accv;
    if (yint) {
        const f32x2 syjv = left ? mk2(rd,  rd2) : sp2(rd2);  // col0: fwd diff
        const f32x2 symv = left ? mk2(rd2, rd ) : sp2(rd2);  // col1: jm==0
        const bool xe = (blockIdx.x == 0) || (blockIdx.x == gridDim.x - 1);
        accv = xe
            ? strip_packed<true >(eps, Wn, i0, j0, left, right, rd2, syjv, symv)
            : strip_packed<false>(eps, Wn, i0, j0, left, right, rd2, syjv, symv);
    } else {
        accv.x = strip_scalar_yb(eps, Hn, Wn, i0, j0,     rd, rd2);
        accv.y = strip_scalar_yb(eps, Hn, Wn, i0, j0 + 1, rd, rd2);
    }

    double acc = (double)accv.x + (double)accv.y;
    #pragma unroll
    for (int off = 32; off > 0; off >>= 1)
        acc += __shfl_down(acc, off, 64);
    __shared__ double lds[BLOCK_X / 64];
    const int lane = tx & 63, wv = tx >> 6;
    if (lane == 0) lds[wv] = acc;
    __syncthreads();
    if (tx == 0) {
        // plain store — NO device-scope atomics/fences (R2/R3/R10 regressions)
        partial[blockIdx.y * gridDim.x + blockIdx.x] =
            lds[0] + lds[1] + lds[2] + lds[3];
    }
}

__global__ __launch_bounds__(256) void curve_finish_kernel(
    const double* __restrict__ partial, int n,
    const float* __restrict__ gs, float* __restrict__ out)
{
    const int tx = threadIdx.x;
    double acc = 0.0;
    for (int idx = tx; idx < n; idx += 256) acc += partial[idx];
    #pragma unroll
    for (int off = 32; off > 0; off >>= 1)
        acc += __shfl_down(acc, off, 64);
    __shared__ double lds[4];
    const int lane = tx & 63, wv = tx >> 6;
    if (lane == 0) lds[wv] = acc;
    __syncthreads();
    if (tx == 0) {
        const double dd = (double)gs[0];
        // x2 for the mirrored half; x d^2 for grid_size^2 (ALPHA=1)
        out[0] = (float)((lds[0] + lds[1] + lds[2] + lds[3]) * 2.0 * dd * dd);
    }
}

extern "C" void kernel_launch(void* const* d_in, const int* in_sizes, int n_in,
                              void* d_out, int out_size, void* d_ws, size_t ws_size,
                              hipStream_t stream) {
    const float* eps = (const float*)d_in[0];
    const float* gs  = (const float*)d_in[1];
    float* out = (float*)d_out;

    const int n = in_sizes[0];
    int Wn = (int)(sqrt((double)n) + 0.5);   // 4096 for 4096x4096
    int Hn = n / Wn;

    const int gx = Wn / (BLOCK_X * 2);               // 8 (assumes divisible)
    const int gy = (Hn + ROWS_PER - 1) / ROWS_PER;   // 128
    const int nb = gx * gy;                          // 1024
    double* partial = (double*)d_ws;   // nb slots, ALL written every launch

    curve_partial_kernel<<<dim3(gx, gy), BLOCK_X, 0, stream>>>(eps, gs, partial, Hn, Wn);
    curve_finish_kernel<<<1, 256, 0, stream>>>(partial, nb, gs, out);
}